// Round 2
// baseline (742.996 us; speedup 1.0000x reference)
//
#include <hip/hip_runtime.h>

#define N_NODES 512
#define C_CH    128
#define D_DIM   16
#define S_SPEC  10

// Symmetrized coefficient tables, o-major inner layout for quarter-contiguous reads.
__device__ float g_coef3[816][112];  // [monomial a<=b<=j][o16*7 + k]
__device__ float g_coef2[136][48];   // [pair a<=b][o16*3 + k]
__device__ float g_coef1[16][16];    // [a][o16]

__device__ __forceinline__ int rfl(int v) { return __builtin_amdgcn_readfirstlane(v); }
__device__ __forceinline__ int ir_of(int o) { return (o >= 9) ? 3 : (o >= 4) ? 2 : (o >= 1) ? 1 : 0; }

// ---------------- precompute kernels ----------------

__global__ void build_coef3(const float* __restrict__ u0, const float* __restrict__ u1,
                            const float* __restrict__ u2, const float* __restrict__ u3) {
  int id = blockIdx.x * 64 + threadIdx.x;
  if (id >= 7 * 816) return;
  int k = id / 816;
  int m = id % 816;
  int mm = m, a = 0, b = 0;
  for (a = 0; a < 16; ++a) { int cnt = (16 - a) * (17 - a) / 2; if (mm < cnt) break; mm -= cnt; }
  for (b = a; b < 16; ++b) { int len = 16 - b; if (mm < len) break; mm -= len; }
  int j = b + mm;
  const float* us[4] = {u0, u1, u2, u3};
  const int dis[4]   = {1, 3, 5, 7};
  const int obase[4] = {0, 1, 4, 9};
  int P[6][3] = {{a,b,j},{a,j,b},{b,a,j},{b,j,a},{j,a,b},{j,b,a}};
  for (int ir = 0; ir < 4; ++ir) {
    int di = dis[ir];
    const float* u = us[ir];
    for (int i = 0; i < di; ++i) {
      float sum = 0.f;
      for (int p = 0; p < 6; ++p) {
        bool dup = false;
        for (int q = 0; q < p; ++q)
          if (P[q][0] == P[p][0] && P[q][1] == P[p][1] && P[q][2] == P[p][2]) { dup = true; break; }
        if (dup) continue;
        sum += u[(((P[p][0] * 16 + P[p][1]) * 16 + P[p][2]) * 7 + k) * di + i];
      }
      g_coef3[m][(obase[ir] + i) * 7 + k] = sum;
    }
  }
}

__global__ void build_coef2(const float* __restrict__ u0, const float* __restrict__ u1,
                            const float* __restrict__ u2, const float* __restrict__ u3) {
  int id = blockIdx.x * 64 + threadIdx.x;
  if (id >= 3 * 136) return;
  int k = id / 136;
  int m = id % 136;
  int mm = m, a = 0;
  for (a = 0; a < 16; ++a) { int len = 16 - a; if (mm < len) break; mm -= len; }
  int b = a + mm;
  const float* us[4] = {u0, u1, u2, u3};
  const int dis[4]   = {1, 3, 5, 7};
  const int obase[4] = {0, 1, 4, 9};
  for (int ir = 0; ir < 4; ++ir) {
    int di = dis[ir];
    const float* u = us[ir];
    for (int i = 0; i < di; ++i) {
      float sum = u[((a * 16 + b) * 3 + k) * di + i];
      if (a != b) sum += u[((b * 16 + a) * 3 + k) * di + i];
      g_coef2[m][(obase[ir] + i) * 3 + k] = sum;
    }
  }
}

__global__ void build_coef1(const float* __restrict__ u0, const float* __restrict__ u1,
                            const float* __restrict__ u2, const float* __restrict__ u3) {
  int a = threadIdx.x;
  if (a >= 16) return;
  const float* us[4] = {u0, u1, u2, u3};
  const int dis[4]   = {1, 3, 5, 7};
  const int obase[4] = {0, 1, 4, 9};
  for (int ir = 0; ir < 4; ++ir) {
    int di = dis[ir];
    for (int i = 0; i < di; ++i)
      g_coef1[a][obase[ir] + i] = us[ir][a * di + i];
  }
}

// ---------------- main heavy kernel: per (node, j-half) partial acc ----------------

#define FMA4(dst, base, r)                         \
  dst[base + 0] = fmaf((r).x, mono, dst[base + 0]); \
  dst[base + 1] = fmaf((r).y, mono, dst[base + 1]); \
  dst[base + 2] = fmaf((r).z, mono, dst[base + 2]); \
  dst[base + 3] = fmaf((r).w, mono, dst[base + 3]);

__global__ __launch_bounds__(512, 6) void eqp_part(
    const float* __restrict__ x, const int* __restrict__ specie,
    const float* __restrict__ w1, const float* __restrict__ w2,
    const float* __restrict__ w3, float* __restrict__ ws) {
  __shared__ float xT[16][128];
  const int t = threadIdx.x;
  const int c = t & 127;
  const int q = t >> 7;               // o-quarter (wave-uniform: 2 waves per q)
  const int n = blockIdx.x;
  const int jh = blockIdx.y;
  const int nsp = gridDim.y;

  {  // stage x[n][c][:] transposed into LDS
    const float4 v = *(const float4*)(x + ((size_t)n * C_CH + c) * D_DIM + q * 4);
    xT[q * 4 + 0][c] = v.x; xT[q * 4 + 1][c] = v.y;
    xT[q * 4 + 2][c] = v.z; xT[q * 4 + 3][c] = v.w;
  }
  __syncthreads();
  const int s = specie[n];

  float o3[28], o2[12], o1[4];
#pragma unroll
  for (int i = 0; i < 28; ++i) o3[i] = 0.f;
#pragma unroll
  for (int i = 0; i < 12; ++i) o2[i] = 0.f;
#pragma unroll
  for (int i = 0; i < 4; ++i) o1[i] = 0.f;

  // ---- order 3: 816 symmetric monomials, j-range split across blockIdx.y ----
  {
    int mab = 0;
    for (int a = 0; a < 16; ++a) {
      float xa = xT[a][c];
      for (int b = a; b < 16; ++b) {
        float xab = xa * xT[b][c];
        int len = 16 - b;
        int mid = b + ((len + ((a + b) & 1)) >> 1);
        int lo = rfl((nsp == 2 && jh == 1) ? mid : b);
        int hi = rfl((nsp == 2 && jh == 0) ? mid : 16);
        const float* crow = &g_coef3[mab + (lo - b)][q * 28];
        for (int j = lo; j < hi; ++j) {
          float mono = xab * xT[j][c];
          const float4* cr = (const float4*)crow;
          float4 r0 = cr[0], r1 = cr[1], r2 = cr[2], r3 = cr[3];
          float4 r4 = cr[4], r5 = cr[5], r6 = cr[6];
          FMA4(o3, 0, r0); FMA4(o3, 4, r1); FMA4(o3, 8, r2); FMA4(o3, 12, r3);
          FMA4(o3, 16, r4); FMA4(o3, 20, r5); FMA4(o3, 24, r6);
          crow += 112;
        }
        mab += len;
      }
    }
  }

  // ---- order 2: 136 symmetric pairs, b-range split across blockIdx.y ----
  {
    int mp = 0;
    for (int a = 0; a < 16; ++a) {
      float xa = xT[a][c];
      int len = 16 - a;
      int mid = a + ((len + (a & 1)) >> 1);
      int lo = rfl((nsp == 2 && jh == 1) ? mid : a);
      int hi = rfl((nsp == 2 && jh == 0) ? mid : 16);
      const float* crow = &g_coef2[mp + (lo - a)][q * 12];
      for (int b = lo; b < hi; ++b) {
        float mono = xa * xT[b][c];
        const float4* cr = (const float4*)crow;
        float4 r0 = cr[0], r1 = cr[1], r2 = cr[2];
        FMA4(o2, 0, r0); FMA4(o2, 4, r1); FMA4(o2, 8, r2);
        crow += 48;
      }
      mp += len;
    }
  }

  // ---- order 1: a-range split across blockIdx.y ----
  {
    int lo = rfl((nsp == 2 && jh == 1) ? 8 : 0);
    int hi = rfl((nsp == 2 && jh == 0) ? 8 : 16);
    for (int a = lo; a < hi; ++a) {
      float xa = xT[a][c];
      const float4 cr = *(const float4*)(&g_coef1[a][q * 4]);
      o1[0] = fmaf(cr.x, xa, o1[0]); o1[1] = fmaf(cr.y, xa, o1[1]);
      o1[2] = fmaf(cr.z, xa, o1[2]); o1[3] = fmaf(cr.w, xa, o1[3]);
    }
  }

  // ---- fold species weights, write partial red to ws: [jh][n][o][c] ----
#pragma unroll
  for (int oo = 0; oo < 4; ++oo) {
    int o = q * 4 + oo;
    int ir = ir_of(o);
    const float* w3p = w3 + ((size_t)(ir * S_SPEC + s) * 7) * C_CH + c;
    const float* w2p = w2 + ((size_t)(ir * S_SPEC + s) * 3) * C_CH + c;
    float acc = w1[(size_t)(ir * S_SPEC + s) * C_CH + c] * o1[oo];
#pragma unroll
    for (int k = 0; k < 3; ++k) acc = fmaf(w2p[k * C_CH], o2[oo * 3 + k], acc);
#pragma unroll
    for (int k = 0; k < 7; ++k) acc = fmaf(w3p[k * C_CH], o3[oo * 7 + k], acc);
    ws[(((size_t)jh * N_NODES + n) * 16 + o) * C_CH + c] = acc;
  }
}

// ---------------- epilogue: sum partials + wlin channel mix ----------------

template <int HH>
__device__ __forceinline__ void lin_half(const float* __restrict__ redS,
                                         const float* __restrict__ wlin,
                                         float* __restrict__ out, int n, int f) {
  constexpr int irOfA[16] = {0,1,1,1,2,2,2,2,2,3,3,3,3,3,3,3};
  constexpr int iOfA[16]  = {0,0,1,2,0,1,2,3,4,0,1,2,3,4,5,6};
  constexpr int diA[4]  = {1, 3, 5, 7};
  constexpr int ooff[4] = {0, 128, 512, 1152};
  float res[8];
#pragma unroll
  for (int oo = 0; oo < 8; ++oo) res[oo] = 0.f;
  for (int cc = 0; cc < 128; ++cc) {
    float wv[4];
#pragma unroll
    for (int ir = 0; ir < 4; ++ir) wv[ir] = 0.f;
    // load only the irs this half needs (compile-time set)
#pragma unroll
    for (int ir = 0; ir < 4; ++ir) {
      bool need = false;
#pragma unroll
      for (int oo = 0; oo < 8; ++oo) need = need || (irOfA[HH * 8 + oo] == ir);
      if (need) wv[ir] = wlin[((size_t)ir * C_CH + cc) * C_CH + f];
    }
#pragma unroll
    for (int oo = 0; oo < 8; ++oo)
      res[oo] = fmaf(redS[(HH * 8 + oo) * 128 + cc], wv[irOfA[HH * 8 + oo]], res[oo]);
  }
  const float inv = 0.08838834764831845f;  // 1/sqrt(128)
  size_t base = (size_t)n * 2048;
#pragma unroll
  for (int oo = 0; oo < 8; ++oo) {
    constexpr int dummy = 0; (void)dummy;
    int o = HH * 8 + oo;
    out[base + ooff[irOfA[o]] + (size_t)f * diA[irOfA[o]] + iOfA[o]] = res[oo] * inv;
  }
}

__global__ __launch_bounds__(256) void eqp_lin(
    const float* __restrict__ ws, const float* __restrict__ wlin,
    float* __restrict__ out, int nsp) {
  __shared__ float redS[2048];  // [o][c]
  const int t = threadIdx.x;
  const int n = blockIdx.x;

  {  // sum the j-half partials into LDS
    const float4* p0 = (const float4*)(ws + (size_t)n * 2048);
    float4 a = p0[t], b = p0[t + 256];
    if (nsp == 2) {
      const float4* p1 = (const float4*)(ws + ((size_t)N_NODES + n) * 2048);
      float4 a1 = p1[t], b1 = p1[t + 256];
      a.x += a1.x; a.y += a1.y; a.z += a1.z; a.w += a1.w;
      b.x += b1.x; b.y += b1.y; b.z += b1.z; b.w += b1.w;
    }
    ((float4*)redS)[t] = a;
    ((float4*)redS)[t + 256] = b;
  }
  __syncthreads();

  const int f = t & 127;
  if ((t >> 7) == 0) lin_half<0>(redS, wlin, out, n, f);
  else               lin_half<1>(redS, wlin, out, n, f);
}

// ---------------- launch ----------------

extern "C" void kernel_launch(void* const* d_in, const int* in_sizes, int n_in,
                              void* d_out, int out_size, void* d_ws, size_t ws_size,
                              hipStream_t stream) {
  const float* x      = (const float*)d_in[0];
  const int*   specie = (const int*)d_in[1];

  const float *u1s[4], *u2s[4], *u3s[4];
  if (in_sizes[3] == 768) {  // interleaved dict order: u1_0,u2_0,u3_0,u1_1,...
    for (int i = 0; i < 4; ++i) {
      u1s[i] = (const float*)d_in[2 + 3 * i];
      u2s[i] = (const float*)d_in[3 + 3 * i];
      u3s[i] = (const float*)d_in[4 + 3 * i];
    }
  } else {                   // grouped order: u1_0..u1_3,u2_0..u2_3,u3_0..u3_3
    for (int i = 0; i < 4; ++i) {
      u1s[i] = (const float*)d_in[2 + i];
      u2s[i] = (const float*)d_in[6 + i];
      u3s[i] = (const float*)d_in[10 + i];
    }
  }
  const float* w1   = (const float*)d_in[14];
  const float* w2   = (const float*)d_in[15];
  const float* w3   = (const float*)d_in[16];
  const float* wlin = (const float*)d_in[17];
  float* out = (float*)d_out;
  float* ws  = (float*)d_ws;

  // 2-way j-split needs 2*512*2048 floats of scratch; fall back to 1 if tight.
  const size_t need2 = 2ull * N_NODES * 2048 * sizeof(float);
  const int nsp = (ws_size >= need2) ? 2 : 1;

  build_coef3<<<(7 * 816 + 63) / 64, 64, 0, stream>>>(u3s[0], u3s[1], u3s[2], u3s[3]);
  build_coef2<<<(3 * 136 + 63) / 64, 64, 0, stream>>>(u2s[0], u2s[1], u2s[2], u2s[3]);
  build_coef1<<<1, 64, 0, stream>>>(u1s[0], u1s[1], u1s[2], u1s[3]);
  eqp_part<<<dim3(N_NODES, nsp), 512, 0, stream>>>(x, specie, w1, w2, w3, ws);
  eqp_lin<<<N_NODES, 256, 0, stream>>>(ws, wlin, out, nsp);
}

// Round 3
// 85.655 us; speedup vs baseline: 8.6743x; 8.6743x over previous
//
#include <hip/hip_runtime.h>

#define N_NODES 512
#define C_CH    128
#define D_DIM   16
#define S_SPEC  10

typedef _Float16 h8 __attribute__((ext_vector_type(8)));
typedef float f32x4 __attribute__((ext_vector_type(4)));

// K layout: rows 0..815 order-3 monomials (a<=b<=j), 816..951 order-2 pairs,
// 952..967 order-1 singles, 968..991 zero pad.  31 K-tiles of 32.
// N layout (k-major): cols 0..111 = k3*16+o (7 Ntiles), 112..159 = k2*16+o (3),
// 160..175 = o (1).  11 Ntiles of 16.
#define KT 31
#define NT 11

// B matrix pre-swizzled into MFMA B-fragment order: [kt][nt][lane][8 fp16]
__device__ h8  g_Bf[KT * NT * 64];
// per-monomial xT element offsets (idx*132), idx in 0..17 (16=ones,17=zeros)
__device__ int g_mA[992], g_mB[992], g_mJ[992];

__device__ __forceinline__ void decode_k(int k, int& ord, int& a, int& b, int& j) {
  if (k < 816) {
    ord = 3; int mm = k;
    for (a = 0; a < 16; ++a) { int cnt = (16 - a) * (17 - a) / 2; if (mm < cnt) break; mm -= cnt; }
    for (b = a; b < 16; ++b) { int len = 16 - b; if (mm < len) break; mm -= len; }
    j = b + mm;
  } else if (k < 952) {
    ord = 2; int mm = k - 816;
    for (a = 0; a < 16; ++a) { int len = 16 - a; if (mm < len) break; mm -= len; }
    b = a + mm; j = 16;
  } else if (k < 968) {
    ord = 1; a = k - 952; b = 16; j = 16;
  } else {
    ord = 0; a = 17; b = 17; j = 17;
  }
}

__global__ void build_mtab() {
  int k = blockIdx.x * 64 + threadIdx.x;
  if (k >= 992) return;
  int ord, a, b, j;
  decode_k(k, ord, a, b, j);
  g_mA[k] = a * 132; g_mB[k] = b * 132; g_mJ[k] = j * 132;
}

// o (0..15) -> (ir, i):  obase = {0,1,4,9}
__device__ __forceinline__ void o_to_iri(int o, int& ir, int& i) {
  if (o >= 9)      { ir = 3; i = o - 9; }
  else if (o >= 4) { ir = 2; i = o - 4; }
  else if (o >= 1) { ir = 1; i = o - 1; }
  else             { ir = 0; i = 0; }
}

__global__ void build_B(const float* __restrict__ u1_0, const float* __restrict__ u1_1,
                        const float* __restrict__ u1_2, const float* __restrict__ u1_3,
                        const float* __restrict__ u2_0, const float* __restrict__ u2_1,
                        const float* __restrict__ u2_2, const float* __restrict__ u2_3,
                        const float* __restrict__ u3_0, const float* __restrict__ u3_1,
                        const float* __restrict__ u3_2, const float* __restrict__ u3_3) {
  const int l  = threadIdx.x;
  const int kt = blockIdx.x;
  const int nt = blockIdx.y;
  const float* u1s[4] = {u1_0, u1_1, u1_2, u1_3};
  const float* u2s[4] = {u2_0, u2_1, u2_2, u2_3};
  const float* u3s[4] = {u3_0, u3_1, u3_2, u3_3};
  const int dis[4] = {1, 3, 5, 7};

  const int o = l & 15;
  int ir, ii; o_to_iri(o, ir, ii);
  const int di = dis[ir];

  h8 v;
#pragma unroll
  for (int i = 0; i < 8; ++i) {
    int k = kt * 32 + (l >> 4) * 8 + i;
    int ord, a, b, j;
    decode_k(k, ord, a, b, j);
    float val = 0.f;
    if (ord == 3 && nt <= 6) {
      int k3 = nt;
      const float* u = u3s[ir];
      int P[6][3] = {{a,b,j},{a,j,b},{b,a,j},{b,j,a},{j,a,b},{j,b,a}};
      for (int p = 0; p < 6; ++p) {
        bool dup = false;
        for (int q = 0; q < p; ++q)
          if (P[q][0] == P[p][0] && P[q][1] == P[p][1] && P[q][2] == P[p][2]) { dup = true; break; }
        if (!dup)
          val += u[(((P[p][0] * 16 + P[p][1]) * 16 + P[p][2]) * 7 + k3) * di + ii];
      }
    } else if (ord == 2 && nt >= 7 && nt <= 9) {
      int k2 = nt - 7;
      const float* u = u2s[ir];
      val = u[((a * 16 + b) * 3 + k2) * di + ii];
      if (a != b) val += u[((b * 16 + a) * 3 + k2) * di + ii];
    } else if (ord == 1 && nt == 10) {
      val = u1s[ir][a * di + ii];
    }
    v[i] = (_Float16)val;
  }
  g_Bf[(kt * NT + nt) * 64 + l] = v;
}

// ---------------- main MFMA kernel: one node per block ----------------

__global__ __launch_bounds__(512, 4) void eqp_mm(
    const float* __restrict__ x, const int* __restrict__ specie,
    const float* __restrict__ w1, const float* __restrict__ w2,
    const float* __restrict__ w3, float* __restrict__ ws) {
  __shared__ float xTs[18 * 132];          // [idx 0..17][c 0..131], idx16=1, idx17=0
  __shared__ _Float16 Ab[2][512 * 8];      // A-stage double buffer, frag-swizzled

  const int t = threadIdx.x;
  const int c = t & 127;
  const int h = t >> 7;          // producer k-group (wave-uniform)
  const int w = t >> 6;          // consumer wave id (0..7)
  const int l = t & 63;
  const int n = blockIdx.x;

  {  // stage xT
    const float4 v = *(const float4*)(x + ((size_t)n * C_CH + c) * D_DIM + h * 4);
    xTs[(h * 4 + 0) * 132 + c] = v.x;
    xTs[(h * 4 + 1) * 132 + c] = v.y;
    xTs[(h * 4 + 2) * 132 + c] = v.z;
    xTs[(h * 4 + 3) * 132 + c] = v.w;
    if (t < 132)                { xTs[16 * 132 + t] = 1.f; }
    else if (t < 264)           { xTs[17 * 132 + (t - 132)] = 0.f; }
  }
  const int s = specie[n];
  const float c4f = 0.f; (void)c4f;

  f32x4 acc[NT];
#pragma unroll
  for (int i = 0; i < NT; ++i) acc[i] = (f32x4){0.f, 0.f, 0.f, 0.f};

  // producer lambda: generate A fragments for tile kt into buffer buf
  auto produce = [&](int kt, int buf) {
    const int k0 = kt * 32 + h * 8;
    const int4* pa = (const int4*)&g_mA[k0];
    const int4* pb = (const int4*)&g_mB[k0];
    const int4* pj = (const int4*)&g_mJ[k0];
    int4 a0 = pa[0], a1 = pa[1];
    int4 b0 = pb[0], b1 = pb[1];
    int4 j0 = pj[0], j1 = pj[1];
    int oa[8] = {a0.x, a0.y, a0.z, a0.w, a1.x, a1.y, a1.z, a1.w};
    int ob[8] = {b0.x, b0.y, b0.z, b0.w, b1.x, b1.y, b1.z, b1.w};
    int oj[8] = {j0.x, j0.y, j0.z, j0.w, j1.x, j1.y, j1.z, j1.w};
    h8 v;
#pragma unroll
    for (int i = 0; i < 8; ++i) {
      float m = xTs[oa[i] + c] * xTs[ob[i] + c] * xTs[oj[i] + c];
      v[i] = (_Float16)m;
    }
    int slot = c * 4 + (h ^ ((c >> 1) & 3));
    *(h8*)&Ab[buf][slot * 8] = v;
  };

  __syncthreads();
  produce(0, 0);
  __syncthreads();

  const int crow = w * 16 + (l & 15);
  const int grp  = l >> 4;
  const int aslot = crow * 4 + (grp ^ ((crow >> 1) & 3));

  for (int kt = 0; kt < KT; ++kt) {
    const int buf = kt & 1;
    // consume current tile
    h8 afrag = *(const h8*)&Ab[buf][aslot * 8];
    const int ntlo = (kt <= 25) ? 0 : ((kt <= 29) ? 7 : 10);
    const int nthi = (kt <= 24) ? 6 : ((kt <= 28) ? 9 : 10);
#pragma unroll
    for (int nt = 0; nt < NT; ++nt) {
      if (nt < ntlo || nt > nthi) continue;
      h8 bfrag = g_Bf[(kt * NT + nt) * 64 + l];
      acc[nt] = __builtin_amdgcn_mfma_f32_16x16x32_f16(afrag, bfrag, acc[nt], 0, 0, 0);
    }
    // produce next tile into other buffer
    if (kt < KT - 1) produce(kt + 1, buf ^ 1);
    __syncthreads();
  }

  // ---- fold species weights from C-fragment, write red[n][o][c] ----
  {
    const int o = l & 15;
    int ir, ii; o_to_iri(o, ir, ii); (void)ii;
    const int cb = w * 16 + grp * 4;   // 4 consecutive channel rows (reg r)
    float tot[4] = {0.f, 0.f, 0.f, 0.f};
#pragma unroll
    for (int k = 0; k < 7; ++k) {
      const float4 wv = *(const float4*)(w3 + ((size_t)(ir * S_SPEC + s) * 7 + k) * C_CH + cb);
      tot[0] = fmaf(wv.x, acc[k][0], tot[0]);
      tot[1] = fmaf(wv.y, acc[k][1], tot[1]);
      tot[2] = fmaf(wv.z, acc[k][2], tot[2]);
      tot[3] = fmaf(wv.w, acc[k][3], tot[3]);
    }
#pragma unroll
    for (int k = 0; k < 3; ++k) {
      const float4 wv = *(const float4*)(w2 + ((size_t)(ir * S_SPEC + s) * 3 + k) * C_CH + cb);
      tot[0] = fmaf(wv.x, acc[7 + k][0], tot[0]);
      tot[1] = fmaf(wv.y, acc[7 + k][1], tot[1]);
      tot[2] = fmaf(wv.z, acc[7 + k][2], tot[2]);
      tot[3] = fmaf(wv.w, acc[7 + k][3], tot[3]);
    }
    {
      const float4 wv = *(const float4*)(w1 + (size_t)(ir * S_SPEC + s) * C_CH + cb);
      tot[0] = fmaf(wv.x, acc[10][0], tot[0]);
      tot[1] = fmaf(wv.y, acc[10][1], tot[1]);
      tot[2] = fmaf(wv.z, acc[10][2], tot[2]);
      tot[3] = fmaf(wv.w, acc[10][3], tot[3]);
    }
    float4 st = {tot[0], tot[1], tot[2], tot[3]};
    *(float4*)(ws + ((size_t)n * 16 + o) * C_CH + cb) = st;
  }
}

// ---------------- epilogue: wlin channel mix (unchanged from R1, nsp=1) ----------------

template <int HH>
__device__ __forceinline__ void lin_half(const float* __restrict__ redS,
                                         const float* __restrict__ wlin,
                                         float* __restrict__ out, int n, int f) {
  constexpr int irOfA[16] = {0,1,1,1,2,2,2,2,2,3,3,3,3,3,3,3};
  constexpr int iOfA[16]  = {0,0,1,2,0,1,2,3,4,0,1,2,3,4,5,6};
  constexpr int diA[4]  = {1, 3, 5, 7};
  constexpr int ooff[4] = {0, 128, 512, 1152};
  float res[8];
#pragma unroll
  for (int oo = 0; oo < 8; ++oo) res[oo] = 0.f;
  for (int cc = 0; cc < 128; ++cc) {
    float wv[4];
#pragma unroll
    for (int ir = 0; ir < 4; ++ir) wv[ir] = 0.f;
#pragma unroll
    for (int ir = 0; ir < 4; ++ir) {
      bool need = false;
#pragma unroll
      for (int oo = 0; oo < 8; ++oo) need = need || (irOfA[HH * 8 + oo] == ir);
      if (need) wv[ir] = wlin[((size_t)ir * C_CH + cc) * C_CH + f];
    }
#pragma unroll
    for (int oo = 0; oo < 8; ++oo)
      res[oo] = fmaf(redS[(HH * 8 + oo) * 128 + cc], wv[irOfA[HH * 8 + oo]], res[oo]);
  }
  const float inv = 0.08838834764831845f;  // 1/sqrt(128)
  size_t base = (size_t)n * 2048;
#pragma unroll
  for (int oo = 0; oo < 8; ++oo) {
    int o = HH * 8 + oo;
    out[base + ooff[irOfA[o]] + (size_t)f * diA[irOfA[o]] + iOfA[o]] = res[oo] * inv;
  }
}

__global__ __launch_bounds__(256) void eqp_lin(
    const float* __restrict__ ws, const float* __restrict__ wlin,
    float* __restrict__ out) {
  __shared__ float redS[2048];  // [o][c]
  const int t = threadIdx.x;
  const int n = blockIdx.x;
  {
    const float4* p0 = (const float4*)(ws + (size_t)n * 2048);
    ((float4*)redS)[t]       = p0[t];
    ((float4*)redS)[t + 256] = p0[t + 256];
  }
  __syncthreads();
  const int f = t & 127;
  if ((t >> 7) == 0) lin_half<0>(redS, wlin, out, n, f);
  else               lin_half<1>(redS, wlin, out, n, f);
}

// ---------------- launch ----------------

extern "C" void kernel_launch(void* const* d_in, const int* in_sizes, int n_in,
                              void* d_out, int out_size, void* d_ws, size_t ws_size,
                              hipStream_t stream) {
  const float* x      = (const float*)d_in[0];
  const int*   specie = (const int*)d_in[1];

  const float *u1s[4], *u2s[4], *u3s[4];
  if (in_sizes[3] == 768) {  // interleaved dict order: u1_0,u2_0,u3_0,u1_1,...
    for (int i = 0; i < 4; ++i) {
      u1s[i] = (const float*)d_in[2 + 3 * i];
      u2s[i] = (const float*)d_in[3 + 3 * i];
      u3s[i] = (const float*)d_in[4 + 3 * i];
    }
  } else {                   // grouped order: u1_0..u1_3,u2_0..u2_3,u3_0..u3_3
    for (int i = 0; i < 4; ++i) {
      u1s[i] = (const float*)d_in[2 + i];
      u2s[i] = (const float*)d_in[6 + i];
      u3s[i] = (const float*)d_in[10 + i];
    }
  }
  const float* w1   = (const float*)d_in[14];
  const float* w2   = (const float*)d_in[15];
  const float* w3   = (const float*)d_in[16];
  const float* wlin = (const float*)d_in[17];
  float* out = (float*)d_out;
  float* ws  = (float*)d_ws;

  build_mtab<<<(992 + 63) / 64, 64, 0, stream>>>();
  build_B<<<dim3(KT, NT), 64, 0, stream>>>(
      u1s[0], u1s[1], u1s[2], u1s[3],
      u2s[0], u2s[1], u2s[2], u2s[3],
      u3s[0], u3s[1], u3s[2], u3s[3]);
  eqp_mm<<<N_NODES, 512, 0, stream>>>(x, specie, w1, w2, w3, ws);
  eqp_lin<<<N_NODES, 256, 0, stream>>>(ws, wlin, out);
}